// Round 9
// baseline (860.811 us; speedup 1.0000x reference)
//
#include <hip/hip_runtime.h>
#include <hip/hip_bf16.h>

// B=32, C=256, H=36, W=64, n=4096.  P = H*W = 2304.  NCOL = B*C = 8192.
#define P_HW   2304
#define NG     4096
#define NCOL   8192
#define KDIM   P_HW
#define NT     72          // K-tiles of 32: 2304/32

typedef __bf16 bf16x8 __attribute__((ext_vector_type(8)));
typedef float  f32x4  __attribute__((ext_vector_type(4)));

__device__ __forceinline__ unsigned short f2bf(float f) {
    union { float f; unsigned int u; } x; x.f = f;
    unsigned int r = x.u + 0x7FFFu + ((x.u >> 16) & 1u);   // RNE
    return (unsigned short)(r >> 16);
}

// ---------------------------------------------------------------------------
// Prep: cast-only (masks generated on the fly inside the GEMM).
// ---------------------------------------------------------------------------
__global__ __launch_bounds__(256) void prep_kernel(
    const float* __restrict__ feat,
    unsigned short* __restrict__ F) {
    const size_t i = ((size_t)blockIdx.x * 256 + threadIdx.x) * 8;
    const float4 v0 = *(const float4*)(feat + i);
    const float4 v1 = *(const float4*)(feat + i + 4);
    union { unsigned short s[8]; uint4 q; } o;
    o.s[0] = f2bf(v0.x); o.s[1] = f2bf(v0.y); o.s[2] = f2bf(v0.z); o.s[3] = f2bf(v0.w);
    o.s[4] = f2bf(v1.x); o.s[5] = f2bf(v1.y); o.s[6] = f2bf(v1.z); o.s[7] = f2bf(v1.w);
    *(uint4*)(F + i) = o.q;
}

// ---------------------------------------------------------------------------
// GEMM v9 = v8 with the ONE fix: __launch_bounds__(512, 1).
// R8 post-mortem: on this toolchain launch_bounds' 2nd arg behaves as
// min-BLOCKS-per-CU (CUDA semantics): (512,4)->VGPR cap 64 (R6), (512,2)
// ->cap 128 (R7/R8).  v8's GEN_A temporaries + acc[8][4] overflowed the
// 128 cap -> acc spilled to scratch (WRITE 171 MB, FETCH 1.29 GB of
// scratch round-trips, MfmaUtil 8%).  LDS=128 KB already limits us to
// 1 block/CU, so the cap was pure harm: (512,1) => 256-VGPR cap, acc
// stays in AGPRs (unified file), GEN_A temps in VGPRs, no spill.
// Everything else byte-identical to v8 (single-variable A/B vs R8, and
// on-the-fly-A A/B vs v4's 159.8 µs).
// ---------------------------------------------------------------------------
__device__ __forceinline__ void async16(const void* g, void* l) {
    __builtin_amdgcn_global_load_lds(
        (__attribute__((address_space(1))) void*)(unsigned long long)g,
        (__attribute__((address_space(3))) void*)(unsigned int)(unsigned long long)l,
        16, 0, 0);
}

__global__ __launch_bounds__(512, 1) void gemm_fused(
    const unsigned short* __restrict__ F,   // [NCOL][K] bf16
    const float* __restrict__ mu,           // [NG][2]
    const float* __restrict__ logsx,
    const float* __restrict__ logsy,
    const float* __restrict__ rho,
    const float* __restrict__ weight,       // [NG][256] fp32
    float* __restrict__ out)                // [32][NG] fp32
{
    // 4 ring buffers; each: A[256][32] + B[256][32] bf16.
    // LDS slot (r, cp) holds global chunk c = cp ^ ((r>>1)&3)  [XOR swizzle].
    __shared__ __align__(16) unsigned short lds[4 * 16384];

    const int tid  = threadIdx.x;            // 0..511
    const int lane = tid & 63;
    const int wid  = tid >> 6;               // 0..7
    const int wr   = wid >> 2;               // 0..1  (M half: 128 rows)
    const int wc   = wid & 3;                // 0..3  (N quarter: 64 cols)
    const int quad = lane >> 4, m = lane & 15;

    const int rowBase = blockIdx.y * 256;    // over NG
    const int colBase = blockIdx.x * 256;    // over NCOL (= b*256)

    // Staging geometry (v4): thread t, round i -> r = i*128 + (t>>2),
    // global chunk c = (t&3) ^ ((t>>3)&3)  [i-invariant].
    const int rA = tid >> 2;
    const int cA = (tid & 3) ^ ((tid >> 3) & 3);
    const unsigned short* pB = F + (size_t)(colBase + rA) * KDIM + cA * 8;

    // Per-block A-row params: this thread owns rows rA0 = tid>>2 and +128.
    float mux[2], muy[2], isx[2], isy[2], rr[2], inv[2];
#pragma unroll
    for (int i = 0; i < 2; ++i) {
        const int n = rowBase + (tid >> 2) + i * 128;
        mux[i] = mu[2 * n]; muy[i] = mu[2 * n + 1];
        isx[i] = 1.0f / (__expf(logsx[n]) + 1e-6f);
        isy[i] = 1.0f / (__expf(logsy[n]) + 1e-6f);
        const float r = tanhf(rho[n]);
        rr[i]  = r;
        inv[i] = 1.0f / (2.0f * (1.0f - r * r + 1e-6f));
    }

    // Generate A-tile KT (k0 = KT*32) into LDS at DST (A-region base).
    // h = p>>6 is tile-constant (32 k's never cross a W=64 row boundary);
    // w-col = (k0&32) + cA*8 + j.  Formula bit-identical to old prep.
#define GEN_A(KT, DST)                                                     \
    {                                                                      \
        const int   k0 = (KT) * 32;                                        \
        const float Yt = -1.0f + (float)(k0 >> 6) * (2.0f / 35.0f);        \
        const int   wb = (k0 & 32) + cA * 8;                               \
        _Pragma("unroll")                                                  \
        for (int i = 0; i < 2; ++i) {                                      \
            const float yc = (Yt - muy[i]) * isy[i];                       \
            union { unsigned short s[8]; uint4 q; } o;                     \
            _Pragma("unroll")                                              \
            for (int j = 0; j < 8; ++j) {                                  \
                const float X  = -1.0f + (float)(wb + j) * (2.0f / 63.0f); \
                const float xc = (X - mux[i]) * isx[i];                    \
                const float A  = xc * xc + yc * yc                         \
                                 - 2.0f * rr[i] * xc * yc;                 \
                o.s[j] = f2bf(__expf(-A * inv[i]));                        \
            }                                                              \
            *(uint4*)&lds[(DST) + i * 4096 + tid * 8] = o.q;               \
        }                                                                  \
    }

    // ds_read: row = band + m (band mult of 16), chunk cp = quad ^ ((m>>1)&3)
    const int sw   = (quad ^ ((m >> 1) & 3)) * 8;
    const int aoff = (wr * 128 + m) * 32 + sw;
    const int boff = (wc * 64  + m) * 32 + sw;

    f32x4 acc[8][4];
#pragma unroll
    for (int i = 0; i < 8; ++i)
#pragma unroll
        for (int j = 0; j < 4; ++j)
            acc[i][j] = (f32x4){0.f, 0.f, 0.f, 0.f};

    // Prologue: A tile0 via mask-gen; B tiles 0,1,2 staged (6 gloads).
    GEN_A(0, 0);
#pragma unroll
    for (int t2 = 0; t2 < 3; ++t2) {
        async16(pB + t2 * 32,              &lds[t2 * 16384 + 8192  + tid * 8]);
        async16(pB + t2 * 32 + 128 * KDIM, &lds[t2 * 16384 + 12288 + tid * 8]);
    }
    asm volatile("s_waitcnt vmcnt(4) lgkmcnt(0)" ::: "memory");
    __builtin_amdgcn_s_barrier();
    asm volatile("" ::: "memory");

    // Main loop: tile t from buf t&3.  A for t+1 generated depth-1 into
    // (t+1)&3 (consumed at t-3).  B for t+3 staged into (t+3)&3 (consumed
    // at t-1).  vmcnt(4) leaves B t+2,t+3 in flight; lgkmcnt(0) drains the
    // A ds_writes before the publishing barrier.
    for (int tt = 0; tt < NT; tt += 4) {
#pragma unroll
        for (int u = 0; u < 4; ++u) {
            const int t    = tt + u;
            const int bo   = u * 16384;              // static
            const int wAbo = ((u + 1) & 3) * 16384;  // static
            const int wBbo = ((u + 3) & 3) * 16384;  // static
            int wA = t + 1; if (wA >= NT) wA -= NT;  // wrap: garbage into
            int wB = t + 3; if (wB >= NT) wB -= NT;  // consumed regions
            const unsigned short* pBw = pB + wB * 32;

            // issue B staging first (max lead), then A mask-gen (VALU work
            // the compiler spreads into MFMA gaps)
            async16(pBw,              &lds[wBbo + 8192  + tid * 8]);
            async16(pBw + 128 * KDIM, &lds[wBbo + 12288 + tid * 8]);
            GEN_A(wA, wAbo);

            // 12 ds_reads + 32 MFMA; compiler interleaves via counted lgkmcnt
            bf16x8 a[8], b[4];
#pragma unroll
            for (int j = 0; j < 4; ++j)
                b[j] = *(const bf16x8*)&lds[bo + 8192 + boff + j * 512];
#pragma unroll
            for (int i = 0; i < 8; ++i)
                a[i] = *(const bf16x8*)&lds[bo + aoff + i * 512];

            __builtin_amdgcn_s_setprio(1);
#pragma unroll
            for (int i = 0; i < 8; ++i)
#pragma unroll
                for (int j = 0; j < 4; ++j)
                    acc[i][j] = __builtin_amdgcn_mfma_f32_16x16x32_bf16(a[i], b[j], acc[i][j], 0, 0, 0);
            __builtin_amdgcn_s_setprio(0);

            asm volatile("s_waitcnt vmcnt(4) lgkmcnt(0)" ::: "memory");
            __builtin_amdgcn_s_barrier();
            asm volatile("" ::: "memory");
        }
    }

    // Drain wrapped garbage (B gloads + A writes) before reusing LDS.
    asm volatile("s_waitcnt vmcnt(0) lgkmcnt(0)" ::: "memory");
    __syncthreads();

    // Epilogue: out[b][n] = sum_c pooled[n][b*256+c] * weight[n][c].
    float* red = (float*)lds;                // [4 wc][256 n_local]
    const int cwbase = wc * 64 + m;
#pragma unroll
    for (int i = 0; i < 8; ++i) {
#pragma unroll
        for (int reg = 0; reg < 4; ++reg) {
            const int nloc = wr * 128 + i * 16 + quad * 4 + reg;
            const float* wrow = weight + (size_t)(rowBase + nloc) * 256 + cwbase;
            float s = 0.f;
#pragma unroll
            for (int j = 0; j < 4; ++j)
                s += acc[i][j][reg] * wrow[j * 16];
            s += __shfl_xor(s, 1);
            s += __shfl_xor(s, 2);
            s += __shfl_xor(s, 4);
            s += __shfl_xor(s, 8);
            if (m == 0)
                red[wc * 256 + nloc] = s;
        }
    }
    __syncthreads();
    if (tid < 256) {
        const float s = red[tid] + red[256 + tid] + red[512 + tid] + red[768 + tid];
        out[(size_t)blockIdx.x * NG + rowBase + tid] = s;
    }
}

// ---------------------------------------------------------------------------
extern "C" void kernel_launch(void* const* d_in, const int* in_sizes, int n_in,
                              void* d_out, int out_size, void* d_ws, size_t ws_size,
                              hipStream_t stream) {
    const float* feat   = (const float*)d_in[0];
    const float* mu     = (const float*)d_in[1];
    const float* logsx  = (const float*)d_in[2];
    const float* logsy  = (const float*)d_in[3];
    const float* rho    = (const float*)d_in[4];
    const float* weight = (const float*)d_in[5];
    float* out = (float*)d_out;

    unsigned short* Fbuf = (unsigned short*)d_ws;   // 8192*2304*2 B (only F now)

    hipLaunchKernelGGL(prep_kernel, dim3(9216), dim3(256), 0, stream, feat, Fbuf);

    hipLaunchKernelGGL(gemm_fused, dim3(NCOL / 256, NG / 256), dim3(512), 0, stream,
                       Fbuf, mu, logsx, logsy, rho, weight, out);
}

// Round 11
// 295.338 us; speedup vs baseline: 2.9147x; 2.9147x over previous
//
#include <hip/hip_runtime.h>
#include <hip/hip_bf16.h>

// B=32, C=256, H=36, W=64, n=4096.  P = H*W = 2304.  NCOL = B*C = 8192.
#define P_HW   2304
#define NG     4096
#define NCOL   8192
#define KDIM   P_HW
#define NKT    36          // K-tiles of 64: 2304/64

typedef __bf16 bf16x8 __attribute__((ext_vector_type(8)));
typedef float  f32x4  __attribute__((ext_vector_type(4)));

__device__ __forceinline__ unsigned short f2bf(float f) {
    union { float f; unsigned int u; } x; x.f = f;
    unsigned int r = x.u + 0x7FFFu + ((x.u >> 16) & 1u);   // RNE
    return (unsigned short)(r >> 16);
}

// ---------------------------------------------------------------------------
// Prep: cast + masks (no zero-out; GEMM epilogue stores directly).
// ---------------------------------------------------------------------------
__global__ __launch_bounds__(256) void prep_kernel(
    const float* __restrict__ feat,
    const float* __restrict__ mu,
    const float* __restrict__ logsx,
    const float* __restrict__ logsy,
    const float* __restrict__ rho,
    unsigned short* __restrict__ F,
    unsigned short* __restrict__ G) {
    const int bid = blockIdx.x;
    const int tid = threadIdx.x;
    if (bid < 9216) {
        const size_t i = ((size_t)bid * 256 + tid) * 8;
        const float4 v0 = *(const float4*)(feat + i);
        const float4 v1 = *(const float4*)(feat + i + 4);
        union { unsigned short s[8]; uint4 q; } o;
        o.s[0] = f2bf(v0.x); o.s[1] = f2bf(v0.y); o.s[2] = f2bf(v0.z); o.s[3] = f2bf(v0.w);
        o.s[4] = f2bf(v1.x); o.s[5] = f2bf(v1.y); o.s[6] = f2bf(v1.z); o.s[7] = f2bf(v1.w);
        *(uint4*)(F + i) = o.q;
    } else {
        const int n = bid - 9216;
        const float mux = mu[2 * n], muy = mu[2 * n + 1];
        const float sx = __expf(logsx[n]) + 1e-6f;
        const float sy = __expf(logsy[n]) + 1e-6f;
        const float r  = tanhf(rho[n]);
        const float inv_den = 1.0f / (2.0f * (1.0f - r * r + 1e-6f));
        const float isx = 1.0f / sx, isy = 1.0f / sy;
        for (int base = tid * 8; base < P_HW; base += 2048) {
            const int h = base >> 6, w0 = base & 63;      // W = 64
            const float Y  = -1.0f + (float)h * (2.0f / 35.0f);
            const float yc = (Y - muy) * isy;
            union { unsigned short s[8]; uint4 q; } o;
#pragma unroll
            for (int j = 0; j < 8; ++j) {
                const float X  = -1.0f + (float)(w0 + j) * (2.0f / 63.0f);
                const float xc = (X - mux) * isx;
                const float A  = xc * xc + yc * yc - 2.0f * r * xc * yc;
                o.s[j] = f2bf(__expf(-A * inv_den));
            }
            *(uint4*)&G[(size_t)n * P_HW + base] = o.q;
        }
    }
}

// ---------------------------------------------------------------------------
// GEMM v11 = v10 with the builtin's offset arg REMOVED (always 0, like the
// verified v7).  R10 post-mortem: v10's only unverified element was the
// assumption that global_load_lds's 4th arg offsets the GLOBAL address; the
// absmax-67 wholesale corruption is consistent with it (also) moving the
// LDS destination.  v11 expresses K-tile offsets as compile-time pointer
// constants (sA0 + KT*64) — ISel folds them into the instruction's offset
// field with verified semantics (m254 mechanism), preserving the address
// diet (8 persistent base pointers, +128 elems/iter, peeled last iter, no
// wrap logic) that kills v7's spill.  Schedule byte-identical to v7/v10.
// ---------------------------------------------------------------------------
__device__ __forceinline__ void async16(const void* g, void* l) {
    __builtin_amdgcn_global_load_lds(
        (__attribute__((address_space(1))) void*)(unsigned long long)g,
        (__attribute__((address_space(3))) void*)(unsigned int)(unsigned long long)l,
        16, 0, 0);
}

__global__ __launch_bounds__(512, 2) void gemm_fused(
    const unsigned short* __restrict__ G,   // [NG][K] bf16
    const unsigned short* __restrict__ F,   // [NCOL][K] bf16
    const float* __restrict__ weight,       // [NG][256] fp32
    float* __restrict__ out)                // [32][NG] fp32
{
    // 2 buffers; each: A[256][64] + B[256][64] bf16 (64 KB).  Row = 128 B.
    // LDS slot (r, cp) holds global chunk c = cp ^ (r&7)  [XOR swizzle].
    __shared__ __align__(16) unsigned short lds[2 * 32768];

    const int tid  = threadIdx.x;            // 0..511
    const int lane = tid & 63;
    const int wid  = tid >> 6;               // 0..7
    const int wr   = wid >> 2;               // 0..1  (M half: 128 rows)
    const int wc   = wid & 3;                // 0..3  (N quarter: 64 cols)
    const int quad = lane >> 4, m = lane & 15;

    const int rowBase = blockIdx.y * 256;    // over NG
    const int colBase = blockIdx.x * 256;    // over NCOL (= b*256)

    // Staging: quarter q = 512 slots of 16B, 1/thread: r = q*64 + (tid>>3),
    // global chunk c = (tid&7) ^ ((tid>>3)&7)  [q-invariant].
    const int rS = tid >> 3;
    const int cS = (tid & 7) ^ (rS & 7);
    // 8 persistent base pointers at K-tile t (advanced +128 elems / iter).
    const unsigned short* sA0 = G + (size_t)(rowBase + 0   + rS) * KDIM + cS * 8;
    const unsigned short* sA1 = G + (size_t)(rowBase + 64  + rS) * KDIM + cS * 8;
    const unsigned short* sA2 = G + (size_t)(rowBase + 128 + rS) * KDIM + cS * 8;
    const unsigned short* sA3 = G + (size_t)(rowBase + 192 + rS) * KDIM + cS * 8;
    const unsigned short* sB0 = F + (size_t)(colBase + 0   + rS) * KDIM + cS * 8;
    const unsigned short* sB1 = F + (size_t)(colBase + 64  + rS) * KDIM + cS * 8;
    const unsigned short* sB2 = F + (size_t)(colBase + 128 + rS) * KDIM + cS * 8;
    const unsigned short* sB3 = F + (size_t)(colBase + 192 + rS) * KDIM + cS * 8;

    // KT = compile-time K-tile delta (elements: KT*64 = KT*128 bytes;
    // ISel folds into the instruction offset field).
#define STG_A(buf, q, KT) async16(sA##q + (KT) * 64, \
        &lds[(buf) * 32768 + (q) * 4096 + tid * 8])
#define STG_B(buf, q, KT) async16(sB##q + (KT) * 64, \
        &lds[(buf) * 32768 + 16384 + (q) * 4096 + tid * 8])

    // ds_read: row = band + m, chunk = kk*4 + quad, swz chunk ^= (m&7)
    const int arow = (wr * 128 + m) * 64;
    const int brow = (wc * 64  + m) * 64;
    const int cs0  = ((quad)     ^ (m & 7)) * 8;   // kk=0
    const int cs1  = ((4 + quad) ^ (m & 7)) * 8;   // kk=1

    f32x4 acc[8][4];
#pragma unroll
    for (int i = 0; i < 8; ++i)
#pragma unroll
        for (int j = 0; j < 4; ++j)
            acc[i][j] = (f32x4){0.f, 0.f, 0.f, 0.f};

    // Prologue: tile0 (8 quarters, KT=0) + tile1's first 6 (KT=1).
    STG_A(0, 0, 0); STG_A(0, 1, 0); STG_A(0, 2, 0); STG_A(0, 3, 0);
    STG_B(0, 0, 0); STG_B(0, 1, 0); STG_B(0, 2, 0); STG_B(0, 3, 0);
    STG_A(1, 0, 1); STG_A(1, 2, 1);
    STG_B(1, 0, 1); STG_B(1, 1, 1);
    STG_A(1, 1, 1); STG_A(1, 3, 1);
    asm volatile("s_waitcnt vmcnt(6)" ::: "memory");
    __builtin_amdgcn_s_barrier();

#define MFMA_Q(IOFF, JOFF, AX, BX)                                         \
    __builtin_amdgcn_s_setprio(1);                                         \
    _Pragma("unroll")                                                      \
    for (int fi = 0; fi < 4; ++fi)                                         \
        _Pragma("unroll")                                                  \
        for (int fj = 0; fj < 2; ++fj)                                     \
            _Pragma("unroll")                                              \
            for (int kk = 0; kk < 2; ++kk)                                 \
                acc[fi + IOFF][fj + JOFF] =                                \
                    __builtin_amdgcn_mfma_f32_16x16x32_bf16(               \
                        AX[fi][kk], BX[fj][kk], acc[fi + IOFF][fj + JOFF], \
                        0, 0, 0);                                          \
    __builtin_amdgcn_s_setprio(0);

#define BARRIER_IN()  __builtin_amdgcn_s_barrier();                        \
                      asm volatile("s_waitcnt lgkmcnt(0)" ::: "memory");
#define BARRIER_OUT() __builtin_amdgcn_s_barrier();

    // One 2-K-tile iteration.  K2T/K3T: K-tile deltas of the tiles being
    // staged (steady: 2/3; peel: 1/1 redundant re-stage of the last tile).
#define PHASES(K2T, K3T)                                                   \
    {                                                                      \
        bf16x8 a[4][2], blo[2][2], bhi[2][2];                              \
        /* P1: tile t (buf0) Q(Mlo,Nlo); finish tile t+1 staging */        \
        _Pragma("unroll")                                                  \
        for (int fi = 0; fi < 4; ++fi) {                                   \
            a[fi][0] = *(const bf16x8*)&lds[arow + fi * 1024 + cs0];       \
            a[fi][1] = *(const bf16x8*)&lds[arow + fi * 1024 + cs1];       \
        }                                                                  \
        _Pragma("unroll")                                                  \
        for (int fj = 0; fj < 2; ++fj) {                                   \
            blo[fj][0] = *(const bf16x8*)&lds[16384 + brow + fj * 1024 + cs0]; \
            blo[fj][1] = *(const bf16x8*)&lds[16384 + brow + fj * 1024 + cs1]; \
        }                                                                  \
        STG_B(1, 2, 1); STG_B(1, 3, 1);                                    \
        BARRIER_IN();  MFMA_Q(0, 0, a, blo);  BARRIER_OUT();               \
        /* P2: Q(Mlo,Nhi) */                                               \
        _Pragma("unroll")                                                  \
        for (int fj = 0; fj < 2; ++fj) {                                   \
            bhi[fj][0] = *(const bf16x8*)&lds[16384 + brow + 2048 + fj * 1024 + cs0]; \
            bhi[fj][1] = *(const bf16x8*)&lds[16384 + brow + 2048 + fj * 1024 + cs1]; \
        }                                                                  \
        STG_A(0, 0, K2T); STG_A(0, 2, K2T);                                \
        BARRIER_IN();  MFMA_Q(0, 2, a, bhi);  BARRIER_OUT();               \
        /* P3: Q(Mhi,Nhi) */                                               \
        _Pragma("unroll")                                                  \
        for (int fi = 0; fi < 4; ++fi) {                                   \
            a[fi][0] = *(const bf16x8*)&lds[arow + 4096 + fi * 1024 + cs0]; \
            a[fi][1] = *(const bf16x8*)&lds[arow + 4096 + fi * 1024 + cs1]; \
        }                                                                  \
        STG_B(0, 0, K2T); STG_B(0, 2, K2T);                                \
        BARRIER_IN();  MFMA_Q(4, 2, a, bhi);  BARRIER_OUT();               \
        /* P4: Q(Mhi,Nlo); tile t+1 landed */                              \
        STG_A(0, 1, K2T); STG_A(0, 3, K2T);                                \
        asm volatile("s_waitcnt vmcnt(6)" ::: "memory");                   \
        BARRIER_IN();  MFMA_Q(4, 0, a, blo);  BARRIER_OUT();               \
        /* P5: tile t+1 (buf1) Q(Mlo,Nlo) */                               \
        _Pragma("unroll")                                                  \
        for (int fi = 0; fi < 4; ++fi) {                                   \
            a[fi][0] = *(const bf16x8*)&lds[32768 + arow + fi * 1024 + cs0]; \
            a[fi][1] = *(const bf16x8*)&lds[32768 + arow + fi * 1024 + cs1]; \
        }                                                                  \
        _Pragma("unroll")                                                  \
        for (int fj = 0; fj < 2; ++fj) {                                   \
            blo[fj][0] = *(const bf16x8*)&lds[32768 + 16384 + brow + fj * 1024 + cs0]; \
            blo[fj][1] = *(const bf16x8*)&lds[32768 + 16384 + brow + fj * 1024 + cs1]; \
        }                                                                  \
        STG_B(0, 1, K2T); STG_B(0, 3, K2T);                                \
        BARRIER_IN();  MFMA_Q(0, 0, a, blo);  BARRIER_OUT();               \
        /* P6: Q(Mlo,Nhi) */                                               \
        _Pragma("unroll")                                                  \
        for (int fj = 0; fj < 2; ++fj) {                                   \
            bhi[fj][0] = *(const bf16x8*)&lds[32768 + 16384 + brow + 2048 + fj * 1024 + cs0]; \
            bhi[fj][1] = *(const bf16x8*)&lds[32768 + 16384 + brow + 2048 + fj * 1024 + cs1]; \
        }                                                                  \
        STG_A(1, 0, K3T); STG_A(1, 2, K3T);                                \
        BARRIER_IN();  MFMA_Q(0, 2, a, bhi);  BARRIER_OUT();               \
        /* P7: Q(Mhi,Nhi) */                                               \
        _Pragma("unroll")                                                  \
        for (int fi = 0; fi < 4; ++fi) {                                   \
            a[fi][0] = *(const bf16x8*)&lds[32768 + arow + 4096 + fi * 1024 + cs0]; \
            a[fi][1] = *(const bf16x8*)&lds[32768 + arow + 4096 + fi * 1024 + cs1]; \
        }                                                                  \
        STG_B(1, 0, K3T); STG_B(1, 1, K3T);                                \
        BARRIER_IN();  MFMA_Q(4, 2, a, bhi);  BARRIER_OUT();               \
        /* P8: Q(Mhi,Nlo); tile t+2 landed */                              \
        STG_A(1, 1, K3T); STG_A(1, 3, K3T);                                \
        asm volatile("s_waitcnt vmcnt(6)" ::: "memory");                   \
        BARRIER_IN();  MFMA_Q(4, 0, a, blo);  BARRIER_OUT();               \
    }

    // Main loop: 17 iters (tiles 0..33), then peeled tiles 34,35 with
    // redundant KT=1 (tile 35) re-stages into consumed / identical slots.
    for (int it = 0; it < NKT / 2 - 1; ++it) {
        PHASES(2, 3);
        sA0 += 128; sA1 += 128; sA2 += 128; sA3 += 128;
        sB0 += 128; sB1 += 128; sB2 += 128; sB3 += 128;
    }
    PHASES(1, 1);

    // Drain the redundant prefetches before reusing LDS.
    asm volatile("s_waitcnt vmcnt(0)" ::: "memory");
    __syncthreads();

    // Epilogue: out[b][n] = sum_c pooled[n][b*256+c] * weight[n][c].
    // acc[i][j][reg] = pooled[rowBase + wr*128 + i*16 + quad*4 + reg]
    //                        [colBase + wc*64 + j*16 + m]
    float* red = (float*)lds;                // [4 wc][256 n_local]
    const int cwbase = wc * 64 + m;
#pragma unroll
    for (int i = 0; i < 8; ++i) {
#pragma unroll
        for (int reg = 0; reg < 4; ++reg) {
            const int nloc = wr * 128 + i * 16 + quad * 4 + reg;
            const float* wrow = weight + (size_t)(rowBase + nloc) * 256 + cwbase;
            float s = 0.f;
#pragma unroll
            for (int j = 0; j < 4; ++j)
                s += acc[i][j][reg] * wrow[j * 16];
            s += __shfl_xor(s, 1);
            s += __shfl_xor(s, 2);
            s += __shfl_xor(s, 4);
            s += __shfl_xor(s, 8);
            if (m == 0)
                red[wc * 256 + nloc] = s;
        }
    }
    __syncthreads();
    if (tid < 256) {
        const float s = red[tid] + red[256 + tid] + red[512 + tid] + red[768 + tid];
        out[(size_t)blockIdx.x * NG + rowBase + tid] = s;
    }
}

// ---------------------------------------------------------------------------
extern "C" void kernel_launch(void* const* d_in, const int* in_sizes, int n_in,
                              void* d_out, int out_size, void* d_ws, size_t ws_size,
                              hipStream_t stream) {
    const float* feat   = (const float*)d_in[0];
    const float* mu     = (const float*)d_in[1];
    const float* logsx  = (const float*)d_in[2];
    const float* logsy  = (const float*)d_in[3];
    const float* rho    = (const float*)d_in[4];
    const float* weight = (const float*)d_in[5];
    float* out = (float*)d_out;

    unsigned short* Gbuf = (unsigned short*)d_ws;                  // 4096*2304*2 B
    unsigned short* Fbuf = Gbuf + (size_t)NG * P_HW;               // 8192*2304*2 B

    hipLaunchKernelGGL(prep_kernel, dim3(13312), dim3(256), 0, stream,
                       feat, mu, logsx, logsy, rho, Fbuf, Gbuf);

    hipLaunchKernelGGL(gemm_fused, dim3(NCOL / 256, NG / 256), dim3(512), 0, stream,
                       Gbuf, Fbuf, weight, out);
}